// Round 2
// baseline (848.841 us; speedup 1.0000x reference)
//
#include <hip/hip_runtime.h>
#include <math.h>

#define TPB 256
#define GTPB 128

namespace {

constexpr int IN_FEAT = 512;
constexpr int HID = 16;

__device__ __forceinline__ void load_edge(const int* __restrict__ ei32,
                                          const long long* __restrict__ ei64,
                                          int flag, int e, int E, int& s, int& d) {
  if (flag) {
    s = (int)ei64[e];
    d = (int)ei64[(long long)E + e];
  } else {
    s = ei32[e];
    d = ei32[(long long)E + e];
  }
}

// ---- edge dtype detect: int64 (all high words zero) vs int32 ----
__global__ void k_detect(const int* __restrict__ ei32, int* __restrict__ flag) {
  __shared__ int red[TPB];
  int t = threadIdx.x;
  int v = 0;
  for (int i = t; i < 2048; i += TPB) v |= ei32[2 * i + 1];
  red[t] = v;
  __syncthreads();
  for (int s = TPB / 2; s > 0; s >>= 1) {
    if (t < s) red[t] |= red[t + s];
    __syncthreads();
  }
  if (t == 0) *flag = (red[0] == 0) ? 1 : 0;  // 1 => int64 layout
}

__global__ void k_zero(int* __restrict__ p, int n) {
  int i = blockIdx.x * TPB + threadIdx.x;
  if (i < n) p[i] = 0;
}

// ---- counting sort by dst: count ----
__global__ void k_count(const int* __restrict__ ei32, const long long* __restrict__ ei64,
                        const int* __restrict__ flag, int* __restrict__ cnt, int E) {
  int e = blockIdx.x * TPB + threadIdx.x;
  if (e >= E) return;
  int s, d;
  load_edge(ei32, ei64, *flag, e, E, s, d);
  atomicAdd(&cnt[d], 1);
}

// ---- scan: 1024 elems/block, 3 phases ----
__global__ void k_scanA(const int* __restrict__ cnt, int* __restrict__ part, int n) {
  __shared__ int red[TPB];
  int t = threadIdx.x, b = blockIdx.x;
  int base = b * 1024 + t * 4;
  int s = 0;
#pragma unroll
  for (int q = 0; q < 4; q++) {
    int i = base + q;
    if (i < n) s += cnt[i];
  }
  red[t] = s;
  __syncthreads();
  for (int st = TPB / 2; st > 0; st >>= 1) {
    if (t < st) red[t] += red[t + st];
    __syncthreads();
  }
  if (t == 0) part[b] = red[0];
}

__global__ void k_scanB(int* __restrict__ part, int nb) {
  __shared__ int sc[128];
  int t = threadIdx.x;
  int v = (t < nb) ? part[t] : 0;
  sc[t] = v;
  __syncthreads();
  for (int st = 1; st < 128; st <<= 1) {
    int add = (t >= st) ? sc[t - st] : 0;
    __syncthreads();
    sc[t] = sc[t] + add;
    __syncthreads();
  }
  if (t < nb) part[t] = sc[t] - v;  // exclusive
}

__global__ void k_scanC(const int* __restrict__ cnt, const int* __restrict__ part,
                        int* __restrict__ rowptr, int* __restrict__ cursor,
                        float* __restrict__ dinv, int n, int E) {
  __shared__ int sc[TPB];
  int t = threadIdx.x, b = blockIdx.x;
  int base = b * 1024 + t * 4;
  int v[4];
  int s = 0;
#pragma unroll
  for (int q = 0; q < 4; q++) {
    int i = base + q;
    v[q] = (i < n) ? cnt[i] : 0;
    s += v[q];
  }
  sc[t] = s;
  __syncthreads();
  for (int st = 1; st < TPB; st <<= 1) {
    int add = (t >= st) ? sc[t - st] : 0;
    __syncthreads();
    sc[t] = sc[t] + add;
    __syncthreads();
  }
  int excl = part[b] + sc[t] - s;
#pragma unroll
  for (int q = 0; q < 4; q++) {
    int i = base + q;
    if (i < n) {
      rowptr[i] = excl;
      cursor[i] = excl;
      dinv[i] = rsqrtf((float)(v[q] + 1));  // +1 self-loop
      excl += v[q];
    }
  }
  if (b == 0 && t == 0) rowptr[n] = E;
}

// ---- counting sort by dst: place src ids ----
__global__ void k_place(const int* __restrict__ ei32, const long long* __restrict__ ei64,
                        const int* __restrict__ flag, int* __restrict__ cursor,
                        int* __restrict__ csr, int E) {
  int e = blockIdx.x * TPB + threadIdx.x;
  if (e >= E) return;
  int s, d;
  load_edge(ei32, ei64, *flag, e, E, s, d);
  int pos = atomicAdd(&cursor[d], 1);
  csr[pos] = s;
}

// ---- layer1 GEMM: hs1 = (x @ W1) * dinv[row] ----
// 128-row tiles, K-chunk 64, 4x4 register block/thread, +4-float row pad.
__global__ __launch_bounds__(GTPB) void k_gemm1(const float* __restrict__ x,
                                                const float* __restrict__ W1,
                                                const float* __restrict__ dinv,
                                                float* __restrict__ hs1, int n) {
  __shared__ float xs[128 * 68];
  __shared__ float wt[16 * 68];
  int t = threadIdx.x;
  int rq = t & 31, cq = t >> 5;
  float acc[4][4] = {};
  int r0 = blockIdx.x * 128;
  const float4* x4 = (const float4*)x;
  for (int ch = 0; ch < 8; ch++) {
    for (int i = t; i < 2048; i += GTPB) {
      int row = i >> 4, cc = i & 15;
      int gr = r0 + row;
      if (gr >= n) gr = n - 1;
      float4 v = x4[(long long)gr * 128 + ch * 16 + cc];
      *(float4*)&xs[row * 68 + cc * 4] = v;
    }
    for (int i = t; i < 1024; i += GTPB) {
      int kl = i >> 4, c = i & 15;
      wt[c * 68 + kl] = W1[(ch * 64 + kl) * 16 + c];
    }
    __syncthreads();
#pragma unroll 4
    for (int kk = 0; kk < 16; kk++) {
      float4 xv[4], wv[4];
#pragma unroll
      for (int ri = 0; ri < 4; ri++) xv[ri] = *(const float4*)&xs[(rq + 32 * ri) * 68 + kk * 4];
#pragma unroll
      for (int ci = 0; ci < 4; ci++) wv[ci] = *(const float4*)&wt[(4 * cq + ci) * 68 + kk * 4];
#pragma unroll
      for (int ri = 0; ri < 4; ri++)
#pragma unroll
        for (int ci = 0; ci < 4; ci++) {
          acc[ri][ci] = fmaf(xv[ri].x, wv[ci].x, acc[ri][ci]);
          acc[ri][ci] = fmaf(xv[ri].y, wv[ci].y, acc[ri][ci]);
          acc[ri][ci] = fmaf(xv[ri].z, wv[ci].z, acc[ri][ci]);
          acc[ri][ci] = fmaf(xv[ri].w, wv[ci].w, acc[ri][ci]);
        }
    }
    __syncthreads();
  }
#pragma unroll
  for (int ri = 0; ri < 4; ri++) {
    int row = r0 + rq + 32 * ri;
    if (row < n) {
      float di = dinv[row];
      float4 v = make_float4(acc[ri][0] * di, acc[ri][1] * di, acc[ri][2] * di, acc[ri][3] * di);
      *(float4*)&hs1[(long long)row * HID + 4 * cq] = v;
    }
  }
}

// ---- gather layer1 + bias + relu: h1[d] = relu(dinv[d]*(hs1[d] + sum_in hs1[s]) + b1) ----
__global__ void k_gather1(const int* __restrict__ rowptr, const int* __restrict__ csr,
                          const float* __restrict__ hs1, const float* __restrict__ dinv,
                          const float* __restrict__ b1, float* __restrict__ h1, int n) {
  int gid = blockIdx.x * TPB + threadIdx.x;
  int d = gid >> 4, f = gid & 15;
  if (d >= n) return;
  float acc = hs1[(long long)d * HID + f];  // self-loop
  int j = rowptr[d], end = rowptr[d + 1];
  for (; j + 4 <= end; j += 4) {
    int s0 = csr[j], s1 = csr[j + 1], s2 = csr[j + 2], s3 = csr[j + 3];
    acc += hs1[(long long)s0 * HID + f];
    acc += hs1[(long long)s1 * HID + f];
    acc += hs1[(long long)s2 * HID + f];
    acc += hs1[(long long)s3 * HID + f];
  }
  for (; j < end; j++) acc += hs1[(long long)csr[j] * HID + f];
  h1[(long long)d * HID + f] = fmaxf(fmaf(dinv[d], acc, b1[f]), 0.f);
}

// ---- layer2 transform: hs2 = (h1 @ W2) * dinv, padded to 8 (col 7 = 0) ----
__global__ void k_layer2(const float* __restrict__ h1, const float* __restrict__ dinv,
                         const float* __restrict__ W2, float* __restrict__ hs2, int n) {
  int i = blockIdx.x * TPB + threadIdx.x;
  if (i >= n) return;
  float di = dinv[i];
  float h[16];
  const float4* tp = (const float4*)(h1 + (long long)i * HID);
#pragma unroll
  for (int q = 0; q < 4; q++) {
    float4 v = tp[q];
    h[4 * q + 0] = v.x;
    h[4 * q + 1] = v.y;
    h[4 * q + 2] = v.z;
    h[4 * q + 3] = v.w;
  }
  float o[8];
#pragma unroll
  for (int j = 0; j < 7; j++) {
    float s = 0.f;
#pragma unroll
    for (int c = 0; c < 16; c++) s = fmaf(h[c], W2[c * 7 + j], s);
    o[j] = s * di;
  }
  o[7] = 0.f;
  float4* hp = (float4*)(hs2 + (long long)i * 8);
  hp[0] = make_float4(o[0], o[1], o[2], o[3]);
  hp[1] = make_float4(o[4], o[5], o[6], o[7]);
}

// ---- gather layer2 + bias + log_softmax ----
__global__ void k_gather2(const int* __restrict__ rowptr, const int* __restrict__ csr,
                          const float* __restrict__ hs2, const float* __restrict__ dinv,
                          const float* __restrict__ b2, float* __restrict__ out, int n) {
  int gid = blockIdx.x * TPB + threadIdx.x;
  int d = gid >> 3, f = gid & 7;
  if (d >= n) return;
  float acc = hs2[(long long)d * 8 + f];  // self-loop
  int j = rowptr[d], end = rowptr[d + 1];
  for (; j + 4 <= end; j += 4) {
    int s0 = csr[j], s1 = csr[j + 1], s2 = csr[j + 2], s3 = csr[j + 3];
    acc += hs2[(long long)s0 * 8 + f];
    acc += hs2[(long long)s1 * 8 + f];
    acc += hs2[(long long)s2 * 8 + f];
    acc += hs2[(long long)s3 * 8 + f];
  }
  for (; j < end; j++) acc += hs2[(long long)csr[j] * 8 + f];
  float v = (f < 7) ? fmaf(dinv[d], acc, b2[f]) : -1e30f;
  float m = v;
#pragma unroll
  for (int mask = 1; mask < 8; mask <<= 1) m = fmaxf(m, __shfl_xor(m, mask, 8));
  float e = (f < 7) ? expf(v - m) : 0.f;
#pragma unroll
  for (int mask = 1; mask < 8; mask <<= 1) e += __shfl_xor(e, mask, 8);
  float lse = m + logf(e);
  if (f < 7) out[(long long)d * 7 + f] = v - lse;
}

}  // namespace

extern "C" void kernel_launch(void* const* d_in, const int* in_sizes, int n_in,
                              void* d_out, int out_size, void* d_ws, size_t ws_size,
                              hipStream_t stream) {
  const float* x = (const float*)d_in[0];
  const int* ei32 = (const int*)d_in[1];
  const long long* ei64 = (const long long*)d_in[1];
  const float* W1 = (const float*)d_in[2];
  const float* b1 = (const float*)d_in[3];
  const float* W2 = (const float*)d_in[4];
  const float* b2 = (const float*)d_in[5];
  float* out = (float*)d_out;

  int n = in_sizes[0] / IN_FEAT;  // 100000
  int E = in_sizes[1] / 2;        // 3200000

  // workspace layout (~30.5 MB)
  char* w = (char*)d_ws;
  int* flag = (int*)w;                     w += 256;
  float* dinv = (float*)w;                 w += (size_t)n * 4;
  int* cnt = (int*)w;                      w += (size_t)n * 4;
  int* rowptr = (int*)w;                   w += ((size_t)n + 1) * 4;
  int* cursor = (int*)w;                   w += (size_t)n * 4 + 4;
  int* part = (int*)w;                     w += 1024;
  int* csr = (int*)w;                      w += (size_t)E * 4;
  float* hs1 = (float*)w;                  w += (size_t)n * HID * 4;
  float* h1 = (float*)w;                   w += (size_t)n * HID * 4;
  float* hs2 = (float*)w;                  w += (size_t)n * 8 * 4;

  int nb_n = (n + TPB - 1) / TPB;
  int nb_e = (E + TPB - 1) / TPB;
  int nb_scan = (n + 1023) / 1024;  // 98
  int nb_gemm = (n + 127) / 128;    // 782
  int nb_g1 = (n * 16 + TPB - 1) / TPB;
  int nb_g2 = (n * 8 + TPB - 1) / TPB;

  hipLaunchKernelGGL(k_detect, dim3(1), dim3(TPB), 0, stream, ei32, flag);
  hipLaunchKernelGGL(k_zero, dim3(nb_n), dim3(TPB), 0, stream, cnt, n);
  hipLaunchKernelGGL(k_count, dim3(nb_e), dim3(TPB), 0, stream, ei32, ei64, flag, cnt, E);
  hipLaunchKernelGGL(k_scanA, dim3(nb_scan), dim3(TPB), 0, stream, cnt, part, n);
  hipLaunchKernelGGL(k_scanB, dim3(1), dim3(128), 0, stream, part, nb_scan);
  hipLaunchKernelGGL(k_scanC, dim3(nb_scan), dim3(TPB), 0, stream, cnt, part, rowptr, cursor, dinv, n, E);
  hipLaunchKernelGGL(k_gemm1, dim3(nb_gemm), dim3(GTPB), 0, stream, x, W1, dinv, hs1, n);
  hipLaunchKernelGGL(k_place, dim3(nb_e), dim3(TPB), 0, stream, ei32, ei64, flag, cursor, csr, E);
  hipLaunchKernelGGL(k_gather1, dim3(nb_g1), dim3(TPB), 0, stream, rowptr, csr, hs1, dinv, b1, h1, n);
  hipLaunchKernelGGL(k_layer2, dim3(nb_n), dim3(TPB), 0, stream, h1, dinv, W2, hs2, n);
  hipLaunchKernelGGL(k_gather2, dim3(nb_g2), dim3(TPB), 0, stream, rowptr, csr, hs2, dinv, b2, out, n);
}